// Round 7
// baseline (192.150 us; speedup 1.0000x reference)
//
#include <hip/hip_runtime.h>
#include <hip/hip_bf16.h>

// y(x) = levels[ #{j : b[j] < x} ] where levels = [0, cumsum(scale)] and
// b[j] = cumsum[j] - scale[j]*0.5 (contraction OFF to match the reference's
// mul-then-sub rounding at bucket boundaries). Index accumulation is
// v_cmp + v_addc (2 VALU/level) instead of cmp+cndmask+add (3 VALU/level);
// the final levels[idx] is one LDS gather (separate pipe, mostly-broadcast).
//
// Round 7: (1) wave-uniform fast path -- full blocks do 4 unguarded
// back-to-back global_load_dwordx4 (real MLP=4; round 6's per-load divergent
// guards forced exec-mask serialization); (2) idx+LDS-gather VALU cut.

typedef float vfloat4 __attribute__((ext_vector_type(4)));

__device__ __forceinline__ unsigned qidx(float x, const float* __restrict__ b) {
    unsigned idx = 0u;
#pragma unroll
    for (int j = 0; j < 15; ++j) {
        idx += (b[j] < x) ? 1u : 0u;   // v_cmp_lt_f32 + v_addc_co_u32
    }
    return idx;
}

__global__ __launch_bounds__(256) void nulsq_quant_kernel(
    const float* __restrict__ x, const float* __restrict__ scale,
    float* __restrict__ y, int n4, int n, int full_blocks) {
#pragma clang fp contract(off)
    __shared__ float levels[16];

    // Boundaries in registers (per-thread, uniform values); levels table in
    // LDS, written with static indices by thread 0 (no scratch).
    float b[15];
    {
        float c = 0.0f;
#pragma unroll
        for (int j = 0; j < 15; ++j) {
            float s = scale[j];       // uniform broadcast loads, L1-cached
            c = c + s;                // cumsum[j], sequential order == jnp.cumsum
            b[j] = c - s * 0.5f;      // mul then sub, no fma
        }
    }
    if (threadIdx.x == 0) {
        float c = 0.0f;
        levels[0] = 0.0f;
#pragma unroll
        for (int j = 0; j < 15; ++j) {
            c = c + scale[j];
            levels[j + 1] = c;        // identical partial sums as reference cumsum
        }
    }
    __syncthreads();

    const vfloat4* __restrict__ x4 = reinterpret_cast<const vfloat4*>(x);
    vfloat4* __restrict__ y4 = reinterpret_cast<vfloat4*>(y);

    const int bx = (int)blockIdx.x;
    const int base = bx * 1024 + (int)threadIdx.x;

    if (bx < full_blocks) {
        // Fast path: no bounds checks -> 4 loads issue back-to-back.
        vfloat4 v0 = x4[base];
        vfloat4 v1 = x4[base + 256];
        vfloat4 v2 = x4[base + 512];
        vfloat4 v3 = x4[base + 768];

        vfloat4 r;
        r.x = levels[qidx(v0.x, b)];
        r.y = levels[qidx(v0.y, b)];
        r.z = levels[qidx(v0.z, b)];
        r.w = levels[qidx(v0.w, b)];
        __builtin_nontemporal_store(r, &y4[base]);

        r.x = levels[qidx(v1.x, b)];
        r.y = levels[qidx(v1.y, b)];
        r.z = levels[qidx(v1.z, b)];
        r.w = levels[qidx(v1.w, b)];
        __builtin_nontemporal_store(r, &y4[base + 256]);

        r.x = levels[qidx(v2.x, b)];
        r.y = levels[qidx(v2.y, b)];
        r.z = levels[qidx(v2.z, b)];
        r.w = levels[qidx(v2.w, b)];
        __builtin_nontemporal_store(r, &y4[base + 512]);

        r.x = levels[qidx(v3.x, b)];
        r.y = levels[qidx(v3.y, b)];
        r.z = levels[qidx(v3.z, b)];
        r.w = levels[qidx(v3.w, b)];
        __builtin_nontemporal_store(r, &y4[base + 768]);
    } else {
        // Guarded tail path (only the last partial block, if any).
#pragma unroll
        for (int k = 0; k < 4; ++k) {
            int fi = base + k * 256;
            if (fi < n4) {
                vfloat4 v = x4[fi];
                vfloat4 r;
                r.x = levels[qidx(v.x, b)];
                r.y = levels[qidx(v.y, b)];
                r.z = levels[qidx(v.z, b)];
                r.w = levels[qidx(v.w, b)];
                __builtin_nontemporal_store(r, &y4[fi]);
            }
        }
        // Scalar remainder for n % 4 != 0 (not hit for this shape).
        int tail = n - n4 * 4;
        if ((int)threadIdx.x < tail && bx == full_blocks) {
            int i = n4 * 4 + (int)threadIdx.x;
            y[i] = levels[qidx(x[i], b)];
        }
    }
}

extern "C" void kernel_launch(void* const* d_in, const int* in_sizes, int n_in,
                              void* d_out, int out_size, void* d_ws, size_t ws_size,
                              hipStream_t stream) {
    const float* x = (const float*)d_in[0];
    const float* scale = (const float*)d_in[1];
    float* y = (float*)d_out;

    int n = in_sizes[0];
    int n4 = n / 4;

    const int block = 256;
    const int f4_per_block = block * 4;            // 1024
    int full_blocks = n4 / f4_per_block;           // blocks with no bounds risk
    int grid = (n4 + f4_per_block - 1) / f4_per_block;
    if (n - n4 * 4 > 0 && grid == full_blocks) grid += 1;  // scalar-tail coverage
    if (grid < 1) grid = 1;

    nulsq_quant_kernel<<<grid, block, 0, stream>>>(x, scale, y, n4, n, full_blocks);
}